// Round 13
// baseline (352.443 us; speedup 1.0000x reference)
//
#include <hip/hip_runtime.h>
#include <math.h>

#define ROWS 16
#define NPAIRS 195
#define NTHREADS 256
#define ROW_OUT 258            // 63 copied + 195 distances
#define NLM 21
#define TILE_F (ROWS * ROW_OUT)   // 4128 floats per tile of output
#define IN_F (ROWS * 63)          // 1008 floats per tile of input
#define GRID 2048                 // 8 blocks/CU on 256 CUs

// ---- compile-time pair table, packed as (i | j<<16) ----
struct CodeTab { unsigned int c[NPAIRS]; };

constexpr CodeTab make_codes() {
    CodeTab t{};
    int n = 0;
    for (int a = 0; a < 20; ++a) {
        bool tip = (a == 4) || (a == 8) || (a == 12) || (a == 16) || (a == 19);
        int start = tip ? a + 1 : a + 2;
        for (int b = start; b < 21; ++b) {
            t.c[n] = (unsigned int)a | ((unsigned int)b << 16);
            ++n;
        }
    }
    return t;
}

__constant__ CodeTab CODES = make_codes();

// thread t<252 owns column col=t%63 of rows r0,r0+4,r0+8,r0+12 (r0=t/63).
// scatter ONLY x,y into xy2 (copy section goes straight to global).
__device__ __forceinline__ void scatter_xy(float2* __restrict__ xy2,
                                           const float v[4], int r0,
                                           int lm, int c3) {
    if (c3 == 0) {
#pragma unroll
        for (int e = 0; e < 4; ++e) xy2[(r0 + 4 * e) * NLM + lm].x = v[e];
    } else if (c3 == 1) {
#pragma unroll
        for (int e = 0; e < 4; ++e) xy2[(r0 + 4 * e) * NLM + lm].y = v[e];
    }
}

// in : [B, 63]  (21 landmarks x (x,y,z))
// out: [B, 258] = [copy of 63 | 195 pairwise 2D distances]
__global__ __launch_bounds__(NTHREADS, 8)
void HandKineticLayer_18545668784560_kernel(const float* __restrict__ in,
                                            float* __restrict__ out,
                                            int B) {
    // Tiny double-buffered landmark store: 2 * 16 * 21 * 8B = 5.4 KB.
    __shared__ float2 xy2[2][ROWS * NLM];

    const int t = threadIdx.x;
    const int ntiles = B / ROWS;

    // load/copy geometry (t < 252), hoisted
    const int r0 = t / 63;
    const int col = t - r0 * 63;
    const int lm = col / 3;
    const int c3 = col - lm * 3;
    // dist geometry: row rr (one 16-lane group per row), pair p = q + 16k
    const int rr = t >> 4;
    const int q = t & 15;

    // ---- prologue: load tile0 into regs, scatter xy into buffer 0 ----
    const int tile0 = blockIdx.x;
    float v[4] = {0.f, 0.f, 0.f, 0.f};
    if (tile0 < ntiles) {
        if (t < 252) {
            const float* __restrict__ ip = in + (size_t)tile0 * IN_F + t;
#pragma unroll
            for (int e = 0; e < 4; ++e)
                v[e] = __builtin_nontemporal_load(ip + 252 * e);
            scatter_xy(xy2[0], v, r0, lm, c3);
        }
        __syncthreads();
    }

    // ---- main loop: ONE barrier per tile ----
    int cur = 0;
    for (int tl = tile0; tl < ntiles; tl += GRID) {
        const int nxt = tl + GRID;
        float vn[4] = {0.f, 0.f, 0.f, 0.f};
        const bool have_next = (nxt < ntiles) && (t < 252);
        if (have_next) {
            const float* __restrict__ ip = in + (size_t)nxt * IN_F + t;
#pragma unroll
            for (int e = 0; e < 4; ++e)
                vn[e] = __builtin_nontemporal_load(ip + 252 * e);
        }

        // copy section: straight from registers (wave covers contiguous runs)
        if (t < 252) {
            float* __restrict__ op = out + (size_t)tl * TILE_F
                                         + (size_t)r0 * ROW_OUT + col;
#pragma unroll
            for (int e = 0; e < 4; ++e)
                op[e * 4 * ROW_OUT] = v[e];
        }

        // distances: read xy2[cur], store straight to global (64B chunks)
        {
            const float2* __restrict__ xr = &xy2[cur][rr * NLM];
            float* __restrict__ dg = out + (size_t)tl * TILE_F
                                         + (size_t)rr * ROW_OUT + 63 + q;
#pragma unroll
            for (int k = 0; k < 13; ++k) {
                if (k < 12 || q < 3) {            // p = q+16k < 195
                    const unsigned int c = CODES.c[q + (k << 4)];
                    const float2 a = xr[c & 0xffu];
                    const float2 b = xr[c >> 16];
                    const float dx = a.x - b.x;
                    const float dy = a.y - b.y;
                    dg[k << 4] = __builtin_amdgcn_sqrtf(dx * dx + dy * dy);
                }
            }
        }

        if (have_next) {
            scatter_xy(xy2[cur ^ 1], vn, r0, lm, c3);   // disjoint from xy2[cur]
        }
        __syncthreads();   // scatter visible; xy2[cur] readers done before its
                           // rewrite 2 iterations later (2 barriers apart)
#pragma unroll
        for (int e = 0; e < 4; ++e) v[e] = vn[e];
        cur ^= 1;
    }

    // ---- tail: partial tile (B % 16 != 0), one block, direct stores ----
    const int rem = B - ntiles * ROWS;
    if (rem > 0 && blockIdx.x == (unsigned)(ntiles % GRID)) {
        const int rowBase = ntiles * ROWS;
        const int nelem = rem * 63;
        for (int g = t; g < nelem; g += NTHREADS) {
            const float val = in[(size_t)rowBase * 63 + g];
            const int row = g / 63;
            const int cc = g - row * 63;
            out[(size_t)(rowBase + row) * ROW_OUT + cc] = val;
            const int lmm = cc / 3;
            const int cc3 = cc - lmm * 3;
            if (cc3 == 0) xy2[0][row * NLM + lmm].x = val;
            else if (cc3 == 1) xy2[0][row * NLM + lmm].y = val;
        }
        __syncthreads();
        const int total = rem * NPAIRS;
        for (int idx = t; idx < total; idx += NTHREADS) {
            const int row = idx / NPAIRS;
            const int p = idx - row * NPAIRS;
            const unsigned int c = CODES.c[p];
            const float2 a = xy2[0][row * NLM + (int)(c & 0xffu)];
            const float2 b = xy2[0][row * NLM + (int)(c >> 16)];
            const float dx = a.x - b.x;
            const float dy = a.y - b.y;
            out[(size_t)(rowBase + row) * ROW_OUT + 63 + p] =
                __builtin_amdgcn_sqrtf(dx * dx + dy * dy);
        }
    }
}

extern "C" void kernel_launch(void* const* d_in, const int* in_sizes, int n_in,
                              void* d_out, int out_size, void* d_ws, size_t ws_size,
                              hipStream_t stream) {
    const float* in = (const float*)d_in[0];
    float* out = (float*)d_out;
    const int B = in_sizes[0] / 63;
    hipLaunchKernelGGL(HandKineticLayer_18545668784560_kernel,
                       dim3(GRID), dim3(NTHREADS), 0, stream,
                       in, out, B);
}

// Round 14
// 256.217 us; speedup vs baseline: 1.3756x; 1.3756x over previous
//
#include <hip/hip_runtime.h>
#include <math.h>

#define ROWS 16
#define NPAIRS 195
#define NTHREADS 256
#define ROW_OUT 258            // 63 copied + 195 distances
#define TILE_F (ROWS * ROW_OUT)   // 4128 floats = 16512 B
#define IN_F (ROWS * 63)          // 1008 floats
#define GRID 2048                 // 8 blocks/CU on 256 CUs

typedef float f32x4 __attribute__((ext_vector_type(4)));

// ---- compile-time pair table, packed as (3i | 3j<<16) : direct col offsets ----
struct CodeTab { unsigned int c[NPAIRS]; };

constexpr CodeTab make_codes() {
    CodeTab t{};
    int n = 0;
    for (int a = 0; a < 20; ++a) {
        bool tip = (a == 4) || (a == 8) || (a == 12) || (a == 16) || (a == 19);
        int start = tip ? a + 1 : a + 2;
        for (int b = start; b < 21; ++b) {
            t.c[n] = (unsigned int)(3 * a) | ((unsigned int)(3 * b) << 16);
            ++n;
        }
    }
    return t;
}

__constant__ CodeTab CODES = make_codes();

// thread t<252 owns column col=t%63 of rows r0,r0+4,r0+8,r0+12 (r0=t/63).
// writes ONLY the tile copy-cols (landmark x,y are read back from there).
__device__ __forceinline__ void scatter_tile(float* __restrict__ tile,
                                             const float v[4], int r0, int col) {
#pragma unroll
    for (int e = 0; e < 4; ++e) {
        tile[(r0 + 4 * e) * ROW_OUT + col] = v[e];
    }
}

// row-grouped: r = t>>4 (16 rows x 16-lane groups), pair p = q + 16k.
// landmarks read straight from the tile's copy columns (x=col 3i, y=3i+1):
// adjacent b32 pairs -> ds_read2_b32 fusion.
__device__ __forceinline__ void compute_dists(float* __restrict__ tile, int t) {
    const int r = t >> 4;
    const int q = t & 15;
    float* __restrict__ row = tile + r * ROW_OUT;     // copy cols + dist cols
#pragma unroll
    for (int k = 0; k < 13; ++k) {
        const int p = q + (k << 4);
        if (k < 12 || q < 3) {              // p < 195
            const unsigned int c = CODES.c[p];
            const int ca = (int)(c & 0xffffu);     // 3*i
            const int cb = (int)(c >> 16);         // 3*j
            const float ax = row[ca], ay = row[ca + 1];
            const float bx = row[cb], by = row[cb + 1];
            const float dx = ax - bx;
            const float dy = ay - by;
            row[63 + p] = __builtin_amdgcn_sqrtf(dx * dx + dy * dy);
        }
    }
}

// in : [B, 63]  (21 landmarks x (x,y,z))
// out: [B, 258] = [copy of 63 | 195 pairwise 2D distances]
__global__ __launch_bounds__(NTHREADS, 8)
void HandKineticLayer_18545668784560_kernel(const float* __restrict__ in,
                                            float* __restrict__ out,
                                            int B) {
    // SINGLE buffer, 16.5 KB -> 8 blocks/CU (wave-limited).
    __shared__ __align__(16) float tile[TILE_F];

    const int t = threadIdx.x;
    const int ntiles = B / ROWS;

    // load/copy geometry (t < 252), hoisted once
    const int r0 = t / 63;
    const int col = t - r0 * 63;

    // ---- prologue: load + scatter first tile's copy cols ----
    const int tile0 = blockIdx.x;
    if (tile0 < ntiles) {
        if (t < 252) {
            const float* __restrict__ ip = in + (size_t)tile0 * IN_F + t;
            float v[4];
#pragma unroll
            for (int e = 0; e < 4; ++e)
                v[e] = __builtin_nontemporal_load(ip + 252 * e);
            scatter_tile(tile, v, r0, col);
        }
        __syncthreads();
    }

    // ---- main loop: prefetch(k+1)->regs || compute(k); store(k); scatter(k+1) ----
    for (int tl = tile0; tl < ntiles; tl += GRID) {
        const int nxt = tl + GRID;
        float vn[4] = {0.f, 0.f, 0.f, 0.f};
        const bool have_next = (nxt < ntiles) && (t < 252);
        if (have_next) {
            const float* __restrict__ ip = in + (size_t)nxt * IN_F + t;
#pragma unroll
            for (int e = 0; e < 4; ++e)
                vn[e] = __builtin_nontemporal_load(ip + 252 * e);
        }

        compute_dists(tile, t);     // reads copy-cols, writes dist-cols
        __syncthreads();            // dists visible before store reads

        {
            const f32x4* __restrict__ tl4 =
                reinterpret_cast<const f32x4*>(&tile[0]);
            f32x4* __restrict__ o4 =
                reinterpret_cast<f32x4*>(out + (size_t)tl * TILE_F);
#pragma unroll
            for (int k = t; k < TILE_F / 4; k += NTHREADS) {
                __builtin_nontemporal_store(tl4[k], &o4[k]);
            }
        }
        __syncthreads();            // all waves done READING tile before overwrite

        if (have_next) {
            scatter_tile(tile, vn, r0, col);
        }
        __syncthreads();            // scatter visible for next compute
    }

    // ---- tail: partial tile (B % 16 != 0), one block, non-pipelined ----
    const int rem = B - ntiles * ROWS;
    if (rem > 0 && blockIdx.x == (unsigned)(ntiles % GRID)) {
        const int rowBase = ntiles * ROWS;
        const int nelem = rem * 63;
        for (int g = t; g < nelem; g += NTHREADS) {
            const float val = in[(size_t)rowBase * 63 + g];
            const int row = g / 63;
            const int cc = g - row * 63;
            tile[row * ROW_OUT + cc] = val;
        }
        __syncthreads();
        const int total = rem * NPAIRS;
        for (int idx = t; idx < total; idx += NTHREADS) {
            const int row = idx / NPAIRS;
            const int p = idx - row * NPAIRS;
            const unsigned int c = CODES.c[p];
            const float* __restrict__ rp = tile + row * ROW_OUT;
            const int ca = (int)(c & 0xffffu);
            const int cb = (int)(c >> 16);
            const float dx = rp[ca] - rp[cb];
            const float dy = rp[ca + 1] - rp[cb + 1];
            tile[row * ROW_OUT + 63 + p] = __builtin_amdgcn_sqrtf(dx * dx + dy * dy);
        }
        __syncthreads();
        const int nout = rem * ROW_OUT;
        for (int k = t; k < nout; k += NTHREADS) {
            out[(size_t)rowBase * ROW_OUT + k] = tile[k];
        }
    }
}

extern "C" void kernel_launch(void* const* d_in, const int* in_sizes, int n_in,
                              void* d_out, int out_size, void* d_ws, size_t ws_size,
                              hipStream_t stream) {
    const float* in = (const float*)d_in[0];
    float* out = (float*)d_out;
    const int B = in_sizes[0] / 63;
    hipLaunchKernelGGL(HandKineticLayer_18545668784560_kernel,
                       dim3(GRID), dim3(NTHREADS), 0, stream,
                       in, out, B);
}